// Round 8
// baseline (1254.100 us; speedup 1.0000x reference)
//
#include <hip/hip_runtime.h>
#include <stdint.h>
#include <string.h>

#define NTOK 8192
#define HID 2048
#define NE 32
#define DFF 768
#define NSLOT 65536
#define NB 256
#define MT 256
#define MAX_TILES 288   // 65536/256 + 32

typedef unsigned short u16;
typedef unsigned int u32;

using f32x4 = __attribute__((ext_vector_type(4))) float;
using f32x16 = __attribute__((ext_vector_type(16))) float;
using bf16x8 = __attribute__((ext_vector_type(8))) short;

static __device__ __forceinline__ u16 f2bf(float f) {
  u32 x = __float_as_uint(f);
  x += 0x7fffu + ((x >> 16) & 1u);
  return (u16)(x >> 16);
}

typedef const __attribute__((address_space(1))) unsigned int* gp_t;
typedef __attribute__((address_space(3))) unsigned int* lp_t;
static __device__ __forceinline__ void gload16(const void* g, void* l) {
  __builtin_amdgcn_global_load_lds((gp_t)g, (lp_t)l, 16, 0, 0);
}

// ---------------- fp32 -> bf16 convert (weights) ----------------
__global__ void convertf2b_kernel(const float* __restrict__ src, u16* __restrict__ dst, int n4) {
  int i = blockIdx.x * blockDim.x + threadIdx.x;
  int stride = gridDim.x * blockDim.x;
  for (; i < n4; i += stride) {
    float4 v = reinterpret_cast<const float4*>(src)[i];
    u32 lo = (u32)f2bf(v.x) | ((u32)f2bf(v.y) << 16);
    u32 hi = (u32)f2bf(v.z) | ((u32)f2bf(v.w) << 16);
    reinterpret_cast<uint2*>(dst)[i] = make_uint2(lo, hi);
  }
}

// ---------------- router: logits + softmax + top8 + reroute (+ x->bf16) ----------------
__global__ void router_kernel(const float* __restrict__ x, const float* __restrict__ gw,
                              const float* __restrict__ sim,
                              int* __restrict__ slot_e, float* __restrict__ slot_w,
                              u16* __restrict__ xb) {
  int t = blockIdx.x;
  __shared__ float xs[HID];
  __shared__ float logits[NE];
  const float* xr = x + (size_t)t * HID;
  for (int i = threadIdx.x; i < HID / 4; i += 256)
    reinterpret_cast<float4*>(xs)[i] = reinterpret_cast<const float4*>(xr)[i];
  __syncthreads();
  {
    int i = threadIdx.x;  // HID/8 == 256
    float4 v0 = reinterpret_cast<float4*>(xs)[i * 2];
    float4 v1 = reinterpret_cast<float4*>(xs)[i * 2 + 1];
    uint4 o;
    o.x = (u32)f2bf(v0.x) | ((u32)f2bf(v0.y) << 16);
    o.y = (u32)f2bf(v0.z) | ((u32)f2bf(v0.w) << 16);
    o.z = (u32)f2bf(v1.x) | ((u32)f2bf(v1.y) << 16);
    o.w = (u32)f2bf(v1.z) | ((u32)f2bf(v1.w) << 16);
    reinterpret_cast<uint4*>(xb + (size_t)t * HID)[i] = o;
  }
  int e = threadIdx.x >> 3, part = threadIdx.x & 7;
  const float4* wv = reinterpret_cast<const float4*>(gw + (size_t)e * HID + part * 256);
  const float4* xv = reinterpret_cast<const float4*>(xs + part * 256);
  float s = 0.f;
#pragma unroll
  for (int j = 0; j < 64; ++j) {
    float4 a = xv[j], b = wv[j];
    s += a.x * b.x + a.y * b.y + a.z * b.z + a.w * b.w;
  }
  s += __shfl_xor(s, 1); s += __shfl_xor(s, 2); s += __shfl_xor(s, 4);
  if (part == 0) logits[e] = s;
  __syncthreads();
  if (threadIdx.x == 0) {
    float l[NE];
#pragma unroll
    for (int i = 0; i < NE; ++i) l[i] = logits[i];
    unsigned mask = 0;
    int idx[8]; float lv[8];
#pragma unroll
    for (int k = 0; k < 8; ++k) {
      float best = -3.4e38f; int bi = 0;
#pragma unroll
      for (int i = 0; i < NE; ++i) {
        bool ok = (((mask >> i) & 1u) == 0u) && (l[i] > best);
        best = ok ? l[i] : best;
        bi = ok ? i : bi;
      }
      idx[k] = bi; lv[k] = best; mask |= (1u << bi);
    }
    float w[8]; float ssum = 0.f;
#pragma unroll
    for (int k = 0; k < 8; ++k) { w[k] = __expf(lv[k] - lv[0]); ssum += w[k]; }
    float inv = 1.f / ssum;
    int base = t * 8;
#pragma unroll
    for (int i = 0; i < 4; ++i) { slot_e[base + i] = idx[i]; slot_w[base + i] = w[i] * inv; }
#pragma unroll
    for (int j = 0; j < 4; ++j) {
      int sj = idx[4 + j];
      float best = -2.f; int bsel = idx[0];
#pragma unroll
      for (int i = 0; i < 4; ++i) {
        int pe = idx[i];
        float sv = sim[sj * NE + pe];
        bool ok = sv > best;
        best = ok ? sv : best;
        bsel = ok ? pe : bsel;
      }
      int ns = (best < 0.5f) ? sj : bsel;
      slot_e[base + 4 + j] = ns; slot_w[base + 4 + j] = w[4 + j] * inv;
    }
  }
}

// ---------------- counting sort: hist / scan / place ----------------
__global__ void hist_kernel(const int* __restrict__ slot_e, int* __restrict__ blockCounts) {
  __shared__ int cnt[NE];
  if (threadIdx.x < NE) cnt[threadIdx.x] = 0;
  __syncthreads();
  int i = blockIdx.x * 256 + threadIdx.x;
  atomicAdd(&cnt[slot_e[i]], 1);
  __syncthreads();
  if (threadIdx.x < NE) blockCounts[threadIdx.x * NB + blockIdx.x] = cnt[threadIdx.x];
}

__global__ void scan_kernel(const int* __restrict__ blockCounts, int* __restrict__ startEB,
                            int* __restrict__ tile_e, int* __restrict__ tile_row0,
                            int* __restrict__ tile_cnt, int* __restrict__ tileCount) {
  __shared__ int totals[NE];
  __shared__ int bases[NE];
  int t = threadIdx.x;
  if (t < NE) {
    int run = 0;
    for (int b = 0; b < NB; ++b) run += blockCounts[t * NB + b];
    totals[t] = run;
  }
  __syncthreads();
  if (t == 0) {
    int base = 0, nt = 0;
    for (int e = 0; e < NE; ++e) {
      bases[e] = base;
      int tot = totals[e];
      for (int i = 0; i < tot; i += MT) {
        tile_e[nt] = e;
        tile_row0[nt] = base + i;
        tile_cnt[nt] = (tot - i < MT) ? (tot - i) : MT;
        ++nt;
      }
      base += tot;
    }
    *tileCount = nt;
  }
  __syncthreads();
  if (t < NE) {
    int run = bases[t];
    for (int b = 0; b < NB; ++b) {
      startEB[t * NB + b] = run;
      run += blockCounts[t * NB + b];
    }
  }
}

__global__ void place_kernel(const int* __restrict__ slot_e, const float* __restrict__ slot_w,
                             const int* __restrict__ startEB,
                             int* __restrict__ perm_token, float* __restrict__ perm_w,
                             int* __restrict__ inv) {
  __shared__ int se[256];
  __shared__ float sw[256];
  int b = blockIdx.x;
  for (int i = threadIdx.x; i < 256; i += 64) {
    se[i] = slot_e[b * 256 + i];
    sw[i] = slot_w[b * 256 + i];
  }
  __syncthreads();
  int e = threadIdx.x;
  if (e < NE) {
    int pos = startEB[e * NB + b];
    for (int i = 0; i < 256; ++i) {
      if (se[i] == e) {
        perm_token[pos] = (b * 256 + i) >> 3;
        perm_w[pos] = sw[i];
        inv[b * 256 + i] = pos;
        ++pos;
      }
    }
  }
}

// ---------------- 4-window 256x256 grouped GEMM, 32x32x16 MFMA ----------------
// One window per (buf,kk=32) region: lgkm-drain + vmcnt(N) + single barrier, then
// two 8-MFMA clusters (kh0, kh1) with staging between. vmcnt(8) steady, 8/8/4/0 tail.
// Frag maps (HW-verified): A/B lane=row/col (lane&31), k-chunk (lane>>5)*8;
// C/D col=lane&31, row=(reg&3)+8*(reg>>2)+4*(lane>>5).

#define MFMA32(A_, B_, C_) __builtin_amdgcn_mfma_f32_32x32x16_bf16(A_, B_, C_, 0, 0, 0)

#define GWIN(BUF, KK, VM, S1, S2)                                                      \
  do {                                                                                 \
    asm volatile("s_waitcnt lgkmcnt(0)" ::: "memory");                                 \
    __builtin_amdgcn_sched_barrier(0);                                                 \
    asm volatile("s_waitcnt vmcnt(" #VM ")" ::: "memory");                             \
    __builtin_amdgcn_s_barrier();                                                      \
    const u16* Ap_ = &SA[BUF][KK][0];                                                  \
    const u16* Bp_ = &SB[BUF][KK][0];                                                  \
    bf16x8 a00_ = *(const bf16x8*)(Ap_ + aoff + 0 * 1024 + slot0);                     \
    bf16x8 a10_ = *(const bf16x8*)(Ap_ + aoff + 1 * 1024 + slot0);                     \
    bf16x8 a20_ = *(const bf16x8*)(Ap_ + aoff + 2 * 1024 + slot0);                     \
    bf16x8 a30_ = *(const bf16x8*)(Ap_ + aoff + 3 * 1024 + slot0);                     \
    bf16x8 b00_ = *(const bf16x8*)(Bp_ + b0off + slot0);                               \
    bf16x8 b10_ = *(const bf16x8*)(Bp_ + b1off + slot0);                               \
    S1;                                                                                \
    __builtin_amdgcn_s_setprio(1);                                                     \
    acc[0][0] = MFMA32(a00_, b00_, acc[0][0]);                                         \
    acc[0][1] = MFMA32(a00_, b10_, acc[0][1]);                                         \
    acc[1][0] = MFMA32(a10_, b00_, acc[1][0]);                                         \
    acc[1][1] = MFMA32(a10_, b10_, acc[1][1]);                                         \
    acc[2][0] = MFMA32(a20_, b00_, acc[2][0]);                                         \
    acc[2][1] = MFMA32(a20_, b10_, acc[2][1]);                                         \
    acc[3][0] = MFMA32(a30_, b00_, acc[3][0]);                                         \
    acc[3][1] = MFMA32(a30_, b10_, acc[3][1]);                                         \
    __builtin_amdgcn_s_setprio(0);                                                     \
    bf16x8 a01_ = *(const bf16x8*)(Ap_ + aoff + 0 * 1024 + slot1);                     \
    bf16x8 a11_ = *(const bf16x8*)(Ap_ + aoff + 1 * 1024 + slot1);                     \
    bf16x8 a21_ = *(const bf16x8*)(Ap_ + aoff + 2 * 1024 + slot1);                     \
    bf16x8 a31_ = *(const bf16x8*)(Ap_ + aoff + 3 * 1024 + slot1);                     \
    bf16x8 b01_ = *(const bf16x8*)(Bp_ + b0off + slot1);                               \
    bf16x8 b11_ = *(const bf16x8*)(Bp_ + b1off + slot1);                               \
    S2;                                                                                \
    __builtin_amdgcn_s_setprio(1);                                                     \
    acc[0][0] = MFMA32(a01_, b01_, acc[0][0]);                                         \
    acc[0][1] = MFMA32(a01_, b11_, acc[0][1]);                                         \
    acc[1][0] = MFMA32(a11_, b01_, acc[1][0]);                                         \
    acc[1][1] = MFMA32(a11_, b11_, acc[1][1]);                                         \
    acc[2][0] = MFMA32(a21_, b01_, acc[2][0]);                                         \
    acc[2][1] = MFMA32(a21_, b11_, acc[2][1]);                                         \
    acc[3][0] = MFMA32(a31_, b01_, acc[3][0]);                                         \
    acc[3][1] = MFMA32(a31_, b11_, acc[3][1]);                                         \
    __builtin_amdgcn_s_setprio(0);                                                     \
  } while (0)

// ---------------- gate_up GEMM: 256 slots x (128 gate + 128 up cols) ----------------
__global__ __launch_bounds__(512, 2) void gu_fast(
    const u16* __restrict__ xb, const u16* __restrict__ wgub,
    const int* __restrict__ perm_token,
    const int* __restrict__ tile_e, const int* __restrict__ tile_row0,
    const int* __restrict__ tile_cnt, const int* __restrict__ tileCount,
    u16* __restrict__ h_perm) {
  // XCD clustering: flat%8 = XCD; give each XCD a contiguous 36-tile chunk.
  int flat = blockIdx.x + blockIdx.y * 6;       // NWG = 6*288 = 1728, %8 == 0
  int xcd = flat & 7;
  int j = flat >> 3;                            // 0..215
  int tile = xcd * 36 + j / 6;
  int n0g = (j % 6) * 128;
  if (tile >= *tileCount) return;
  int e = tile_e[tile], row0 = tile_row0[tile], cnt = tile_cnt[tile];
  __shared__ __align__(16) u16 SA[2][2][8192];   // [buf][kk][256 rows x 32 K]
  __shared__ __align__(16) u16 SB[2][2][8192];   // rows 0-127 gate, 128-255 up
  __shared__ int toks[256];
  int tid = threadIdx.x;
  if (tid < 256) {
    int idx = row0 + tid;
    if (idx > NSLOT - 1) idx = NSLOT - 1;
    toks[tid] = perm_token[idx];
  }
  __syncthreads();
  int wave = tid >> 6, lane = tid & 63;
  int wr = wave >> 2, wc = wave & 3;
  int cl = lane & 31, hi = lane >> 5;
  int sr0 = tid >> 2;                       // rows 0..127 (+128 for 2nd load)
  int sc0 = (tid & 3) ^ ((tid >> 3) & 3);   // pre-swizzled K-chunk
  const u16* gA0 = xb + (size_t)toks[sr0] * HID + sc0 * 8;
  const u16* gA1 = xb + (size_t)toks[128 + sr0] * HID + sc0 * 8;
  const u16* wgb = wgub + (size_t)e * (2 * DFF) * HID;
  const u16* gB0 = wgb + (size_t)(n0g + sr0) * HID + sc0 * 8;          // gate row
  const u16* gB1 = wgb + (size_t)(DFF + n0g + sr0) * HID + sc0 * 8;    // up row
  int d0 = tid * 8, d1 = 4096 + tid * 8;    // linear LDS dests (u16 units)

  // frag read offsets (u16 units); storage swizzle: chunk c of row r at slot c^((r>>1)&3)
  int key = (cl >> 1) & 3;
  int slot0 = (hi ^ key) * 8;               // kh=0: logical chunk = hi
  int slot1 = ((2 + hi) ^ key) * 8;         // kh=1: logical chunk = 2+hi
  int aoff = (wr * 128 + cl) * 32;
  int b0off = (wc * 32 + cl) * 32;          // gate tile
  int b1off = (128 + wc * 32 + cl) * 32;    // up tile

  f32x16 acc[4][2];
#pragma unroll
  for (int m = 0; m < 4; ++m)
#pragma unroll
    for (int n = 0; n < 2; ++n)
#pragma unroll
      for (int r = 0; r < 16; ++r) acc[m][n][r] = 0.f;

#define GU_SGA(BUF, KK, KT) do { \
    gload16(gA0 + (KT) + (KK) * 32, &SA[BUF][KK][d0]); \
    gload16(gA1 + (KT) + (KK) * 32, &SA[BUF][KK][d1]); } while (0)
#define GU_SGB(BUF, KK, KT) do { \
    gload16(gB0 + (KT) + (KK) * 32, &SB[BUF][KK][d0]); \
    gload16(gB1 + (KT) + (KK) * 32, &SB[BUF][KK][d1]); } while (0)

  // prologue: t0 full (buf0), t1.kk0 (buf1) = 12 loads in flight
  GU_SGA(0, 0, 0); GU_SGB(0, 0, 0);
  GU_SGA(0, 1, 0); GU_SGB(0, 1, 0);
  GU_SGA(1, 0, 64); GU_SGB(1, 0, 64);

  const int NKT = HID / 64;   // 32
  const int NI = NKT / 2;     // 16
  for (int it = 0; it < NI - 1; ++it) {
    int ktA = (2 * it + 1) * 64;
    int ktB = (2 * it + 2) * 64;
    int ktC = (2 * it + 3) * 64;
    GWIN(0, 0, 8, GU_SGA(1, 1, ktA), GU_SGB(1, 1, ktA));
    GWIN(0, 1, 8, GU_SGA(0, 0, ktB), GU_SGB(0, 0, ktB));
    GWIN(1, 0, 8, GU_SGA(0, 1, ktB), GU_SGB(0, 1, ktB));
    GWIN(1, 1, 8, GU_SGA(1, 0, ktC), GU_SGB(1, 0, ktC));
  }
  {
    int ktA = (2 * (NI - 1) + 1) * 64;
    GWIN(0, 0, 8, GU_SGA(1, 1, ktA), GU_SGB(1, 1, ktA));
    GWIN(0, 1, 8, (void)0, (void)0);
    GWIN(1, 0, 4, (void)0, (void)0);
    GWIN(1, 1, 0, (void)0, (void)0);
  }

  // epilogue: h = silu(g)*u ; acc[m][0]=gate, acc[m][1]=up (same lane/col pairing)
#pragma unroll
  for (int m = 0; m < 4; ++m)
#pragma unroll
    for (int r = 0; r < 16; ++r) {
      int row = wr * 128 + m * 32 + (r & 3) + 8 * (r >> 2) + 4 * hi;
      if (row < cnt) {
        int col = n0g + wc * 32 + cl;
        float g = acc[m][0][r], u = acc[m][1][r];
        float h = g / (1.f + __expf(-g)) * u;
        h_perm[(size_t)(row0 + row) * DFF + col] = f2bf(h);
      }
    }
#undef GU_SGA
#undef GU_SGB
}

// ---------------- down GEMM: 256 slots x 256 hid cols -> yp (fp16) ----------------
__global__ __launch_bounds__(512, 2) void down_fast(
    const u16* __restrict__ h_perm, const u16* __restrict__ wdb,
    const float* __restrict__ perm_w,
    const int* __restrict__ tile_e, const int* __restrict__ tile_row0,
    const int* __restrict__ tile_cnt, const int* __restrict__ tileCount,
    _Float16* __restrict__ yp) {
  int flat = blockIdx.x + blockIdx.y * 8;       // NWG = 8*288 = 2304, %8 == 0
  int xcd = flat & 7;
  int j = flat >> 3;                            // 0..287
  int tile = xcd * 36 + j / 8;
  int n0 = (j % 8) * 256;
  if (tile >= *tileCount) return;
  int e = tile_e[tile], row0 = tile_row0[tile], cnt = tile_cnt[tile];
  __shared__ __align__(16) u16 SA[2][2][8192];
  __shared__ __align__(16) u16 SB[2][2][8192];
  __shared__ float wts[256];
  int tid = threadIdx.x;
  if (tid < 256) {
    int idx = row0 + tid;
    if (idx > NSLOT - 1) idx = NSLOT - 1;
    wts[tid] = perm_w[idx];
  }
  __syncthreads();
  int wave = tid >> 6, lane = tid & 63;
  int wr = wave >> 2, wc = wave & 3;
  int cl = lane & 31, hi = lane >> 5;
  int sr0 = tid >> 2;
  int sc0 = (tid & 3) ^ ((tid >> 3) & 3);
  int ia0 = row0 + sr0;       if (ia0 > NSLOT - 1) ia0 = NSLOT - 1;
  int ia1 = row0 + 128 + sr0; if (ia1 > NSLOT - 1) ia1 = NSLOT - 1;
  const u16* gA0 = h_perm + (size_t)ia0 * DFF + sc0 * 8;
  const u16* gA1 = h_perm + (size_t)ia1 * DFF + sc0 * 8;
  const u16* wb = wdb + (size_t)e * HID * DFF;
  const u16* gB0 = wb + (size_t)(n0 + sr0) * DFF + sc0 * 8;
  const u16* gB1 = wb + (size_t)(n0 + 128 + sr0) * DFF + sc0 * 8;
  int d0 = tid * 8, d1 = 4096 + tid * 8;

  int key = (cl >> 1) & 3;
  int slot0 = (hi ^ key) * 8;
  int slot1 = ((2 + hi) ^ key) * 8;
  int aoff = (wr * 128 + cl) * 32;
  int b0off = (wc * 64 + cl) * 32;
  int b1off = (wc * 64 + 32 + cl) * 32;

  f32x16 acc[4][2];
#pragma unroll
  for (int m = 0; m < 4; ++m)
#pragma unroll
    for (int n = 0; n < 2; ++n)
#pragma unroll
      for (int r = 0; r < 16; ++r) acc[m][n][r] = 0.f;

#define DN_SGA(BUF, KK, KT) do { \
    gload16(gA0 + (KT) + (KK) * 32, &SA[BUF][KK][d0]); \
    gload16(gA1 + (KT) + (KK) * 32, &SA[BUF][KK][d1]); } while (0)
#define DN_SGB(BUF, KK, KT) do { \
    gload16(gB0 + (KT) + (KK) * 32, &SB[BUF][KK][d0]); \
    gload16(gB1 + (KT) + (KK) * 32, &SB[BUF][KK][d1]); } while (0)

  DN_SGA(0, 0, 0); DN_SGB(0, 0, 0);
  DN_SGA(0, 1, 0); DN_SGB(0, 1, 0);
  DN_SGA(1, 0, 64); DN_SGB(1, 0, 64);

  const int NKT = DFF / 64;   // 12
  const int NI = NKT / 2;     // 6
  for (int it = 0; it < NI - 1; ++it) {
    int ktA = (2 * it + 1) * 64;
    int ktB = (2 * it + 2) * 64;
    int ktC = (2 * it + 3) * 64;
    GWIN(0, 0, 8, DN_SGA(1, 1, ktA), DN_SGB(1, 1, ktA));
    GWIN(0, 1, 8, DN_SGA(0, 0, ktB), DN_SGB(0, 0, ktB));
    GWIN(1, 0, 8, DN_SGA(0, 1, ktB), DN_SGB(0, 1, ktB));
    GWIN(1, 1, 8, DN_SGA(1, 0, ktC), DN_SGB(1, 0, ktC));
  }
  {
    int ktA = (2 * (NI - 1) + 1) * 64;
    GWIN(0, 0, 8, DN_SGA(1, 1, ktA), DN_SGB(1, 1, ktA));
    GWIN(0, 1, 8, (void)0, (void)0);
    GWIN(1, 0, 4, (void)0, (void)0);
    GWIN(1, 1, 0, (void)0, (void)0);
  }

#pragma unroll
  for (int m = 0; m < 4; ++m)
#pragma unroll
    for (int r = 0; r < 16; ++r) {
      int row = wr * 128 + m * 32 + (r & 3) + 8 * (r >> 2) + 4 * hi;
      if (row < cnt) {
        float wt = wts[row];
        int col = n0 + wc * 64 + cl;
        yp[(size_t)(row0 + row) * HID + col] = (_Float16)(acc[m][0][r] * wt);
        yp[(size_t)(row0 + row) * HID + col + 32] = (_Float16)(acc[m][1][r] * wt);
      }
    }
#undef DN_SGA
#undef DN_SGB
}

// ---------------- per-token gather-reduce of 8 slots ----------------
__global__ void reduce_kernel(const _Float16* __restrict__ yp, const int* __restrict__ inv,
                              float* __restrict__ y) {
  int t = blockIdx.x;
  __shared__ int pos[8];
  if (threadIdx.x < 8) pos[threadIdx.x] = inv[t * 8 + threadIdx.x];
  __syncthreads();
  int c = threadIdx.x * 8;
  float s[8] = {0.f, 0.f, 0.f, 0.f, 0.f, 0.f, 0.f, 0.f};
#pragma unroll
  for (int j = 0; j < 8; ++j) {
    uint4 v = *reinterpret_cast<const uint4*>(yp + (size_t)pos[j] * HID + c);
    const u16* p = reinterpret_cast<const u16*>(&v);
#pragma unroll
    for (int k = 0; k < 8; ++k) {
      _Float16 h;
      u16 us = p[k];
      __builtin_memcpy(&h, &us, 2);
      s[k] += (float)h;
    }
  }
  float* yo = y + (size_t)t * HID + c;
  float4 o0 = {s[0], s[1], s[2], s[3]};
  float4 o1 = {s[4], s[5], s[6], s[7]};
  *reinterpret_cast<float4*>(yo) = o0;
  *reinterpret_cast<float4*>(yo + 4) = o1;
}

extern "C" void kernel_launch(void* const* d_in, const int* in_sizes, int n_in,
                              void* d_out, int out_size, void* d_ws, size_t ws_size,
                              hipStream_t stream) {
  const float* x = (const float*)d_in[0];
  const float* gw = (const float*)d_in[1];
  const float* wgu = (const float*)d_in[2];
  const float* wd = (const float*)d_in[3];
  const float* sim = (const float*)d_in[4];
  float* y = (float*)d_out;

  char* ws = (char*)d_ws;
  size_t off = 0;
  auto alloc = [&](size_t bytes) {
    char* p = ws + off;
    off += (bytes + 255) & ~(size_t)255;
    return p;
  };
  u16* xb = (u16*)alloc((size_t)NTOK * HID * 2);
  u16* h_perm = (u16*)alloc((size_t)NSLOT * DFF * 2);
  int* slot_e = (int*)alloc(NSLOT * 4);
  float* slot_w = (float*)alloc(NSLOT * 4);
  int* perm_token = (int*)alloc(NSLOT * 4);
  float* perm_w = (float*)alloc(NSLOT * 4);
  int* inv = (int*)alloc(NSLOT * 4);
  int* blockCounts = (int*)alloc(NE * NB * 4);
  int* startEB = (int*)alloc(NE * NB * 4);
  int* tile_e = (int*)alloc(MAX_TILES * 4);
  int* tile_row0 = (int*)alloc(MAX_TILES * 4);
  int* tile_cnt = (int*)alloc(MAX_TILES * 4);
  int* tileCount = (int*)alloc(4);

  // bf16 weights + fp16 per-slot down output (yp aliases wgu_b region)
  size_t wgu_elems = (size_t)NE * 2 * DFF * HID;
  size_t wd_elems = (size_t)NE * HID * DFF;
  size_t region_bytes = (size_t)NSLOT * HID * 2;  // yp (268MB) > wgu_b (201MB)
  u16* wd_b = (u16*)alloc(wd_elems * 2);
  char* region = alloc(region_bytes);
  u16* wgu_b = (u16*)region;
  _Float16* yp = (_Float16*)region;
  if (off > ws_size) return;  // insufficient workspace: fail loudly

  router_kernel<<<NTOK, 256, 0, stream>>>(x, gw, sim, slot_e, slot_w, xb);
  hist_kernel<<<NB, 256, 0, stream>>>(slot_e, blockCounts);
  scan_kernel<<<1, 64, 0, stream>>>(blockCounts, startEB, tile_e, tile_row0, tile_cnt, tileCount);
  place_kernel<<<NB, 64, 0, stream>>>(slot_e, slot_w, startEB, perm_token, perm_w, inv);

  convertf2b_kernel<<<4096, 256, 0, stream>>>(wgu, wgu_b, (int)(wgu_elems / 4));
  convertf2b_kernel<<<4096, 256, 0, stream>>>(wd, wd_b, (int)(wd_elems / 4));
  gu_fast<<<dim3(DFF / 128, MAX_TILES), 512, 0, stream>>>(
      xb, wgu_b, perm_token, tile_e, tile_row0, tile_cnt, tileCount, h_perm);
  down_fast<<<dim3(HID / 256, MAX_TILES), 512, 0, stream>>>(
      h_perm, wd_b, perm_w, tile_e, tile_row0, tile_cnt, tileCount, yp);
  reduce_kernel<<<NTOK, 256, 0, stream>>>(yp, inv, y);
}

// Round 9
// 1204.856 us; speedup vs baseline: 1.0409x; 1.0409x over previous
//
#include <hip/hip_runtime.h>
#include <stdint.h>
#include <string.h>

#define NTOK 8192
#define HID 2048
#define NE 32
#define DFF 768
#define NSLOT 65536
#define NB 256
#define MT 256
#define MAX_TILES 288   // 65536/256 + 32

typedef unsigned short u16;
typedef unsigned int u32;

using f32x4 = __attribute__((ext_vector_type(4))) float;
using bf16x8 = __attribute__((ext_vector_type(8))) short;

static __device__ __forceinline__ u16 f2bf(float f) {
  u32 x = __float_as_uint(f);
  x += 0x7fffu + ((x >> 16) & 1u);
  return (u16)(x >> 16);
}

typedef const __attribute__((address_space(1))) unsigned int* gp_t;
typedef __attribute__((address_space(3))) unsigned int* lp_t;
static __device__ __forceinline__ void gload16(const void* g, void* l) {
  __builtin_amdgcn_global_load_lds((gp_t)g, (lp_t)l, 16, 0, 0);
}

// ---------------- fp32 -> bf16 convert (both weight tensors, one launch) ----------------
__global__ void convert2_kernel(const float* __restrict__ s1, u16* __restrict__ d1, int n1,
                                const float* __restrict__ s2, u16* __restrict__ d2, int n2) {
  int i = blockIdx.x * blockDim.x + threadIdx.x;
  int stride = gridDim.x * blockDim.x;
  int total = n1 + n2;
  for (; i < total; i += stride) {
    const float* src = (i < n1) ? s1 : s2;
    u16* dst = (i < n1) ? d1 : d2;
    int k = (i < n1) ? i : (i - n1);
    float4 v = reinterpret_cast<const float4*>(src)[k];
    u32 lo = (u32)f2bf(v.x) | ((u32)f2bf(v.y) << 16);
    u32 hi = (u32)f2bf(v.z) | ((u32)f2bf(v.w) << 16);
    reinterpret_cast<uint2*>(dst)[k] = make_uint2(lo, hi);
  }
}

// ---------------- router: logits + softmax + top8 + reroute (+ x->bf16) ----------------
// top-8 selection wave-parallelized: 64-lane butterfly argmax, tie -> lower index
// (identical to serial first-max scan semantics).
__global__ void router_kernel(const float* __restrict__ x, const float* __restrict__ gw,
                              const float* __restrict__ sim,
                              int* __restrict__ slot_e, float* __restrict__ slot_w,
                              u16* __restrict__ xb) {
  int t = blockIdx.x;
  __shared__ float xs[HID];
  __shared__ float logits[NE];
  const float* xr = x + (size_t)t * HID;
  for (int i = threadIdx.x; i < HID / 4; i += 256)
    reinterpret_cast<float4*>(xs)[i] = reinterpret_cast<const float4*>(xr)[i];
  __syncthreads();
  {
    int i = threadIdx.x;  // HID/8 == 256
    float4 v0 = reinterpret_cast<float4*>(xs)[i * 2];
    float4 v1 = reinterpret_cast<float4*>(xs)[i * 2 + 1];
    uint4 o;
    o.x = (u32)f2bf(v0.x) | ((u32)f2bf(v0.y) << 16);
    o.y = (u32)f2bf(v0.z) | ((u32)f2bf(v0.w) << 16);
    o.z = (u32)f2bf(v1.x) | ((u32)f2bf(v1.y) << 16);
    o.w = (u32)f2bf(v1.z) | ((u32)f2bf(v1.w) << 16);
    reinterpret_cast<uint4*>(xb + (size_t)t * HID)[i] = o;
  }
  int e = threadIdx.x >> 3, part = threadIdx.x & 7;
  const float4* wv = reinterpret_cast<const float4*>(gw + (size_t)e * HID + part * 256);
  const float4* xv = reinterpret_cast<const float4*>(xs + part * 256);
  float s = 0.f;
#pragma unroll
  for (int j = 0; j < 64; ++j) {
    float4 a = xv[j], b = wv[j];
    s += a.x * b.x + a.y * b.y + a.z * b.z + a.w * b.w;
  }
  s += __shfl_xor(s, 1); s += __shfl_xor(s, 2); s += __shfl_xor(s, 4);
  if (part == 0) logits[e] = s;
  __syncthreads();
  if (threadIdx.x < 64) {
    int lane = threadIdx.x;
    float myv = (lane < NE) ? logits[lane] : -3.4e38f;
    int myi = lane;
    float cur = myv;
    int idx[8]; float lv[8];
#pragma unroll
    for (int k = 0; k < 8; ++k) {
      float bv = cur; int bi = myi;
#pragma unroll
      for (int off = 32; off; off >>= 1) {
        float ov = __shfl_xor(bv, off);
        int oi = __shfl_xor(bi, off);
        if (ov > bv || (ov == bv && oi < bi)) { bv = ov; bi = oi; }
      }
      idx[k] = bi; lv[k] = bv;          // uniform across lanes (butterfly)
      if (myi == bi) cur = -3.4e38f;    // mask winner
    }
    float w[8]; float ssum = 0.f;
#pragma unroll
    for (int k = 0; k < 8; ++k) { w[k] = __expf(lv[k] - lv[0]); ssum += w[k]; }
    float inv = 1.f / ssum;
    int base = t * 8;
    if (lane < 4) {
      // primary slots
      slot_e[base + lane] = idx[lane];
      slot_w[base + lane] = w[lane] * inv;
      // secondary reroute (lane j handles sec j)
      int sj = idx[4 + lane];
      float best = -2.f; int bsel = idx[0];
#pragma unroll
      for (int i = 0; i < 4; ++i) {
        int pe = idx[i];
        float sv = sim[sj * NE + pe];
        bool ok = sv > best;              // strict > == argmax first-max
        best = ok ? sv : best;
        bsel = ok ? pe : bsel;
      }
      int ns = (best < 0.5f) ? sj : bsel;
      slot_e[base + 4 + lane] = ns;
      slot_w[base + 4 + lane] = w[4 + lane] * inv;
    }
  }
}

// ---------------- counting sort: hist / scan / place ----------------
__global__ void hist_kernel(const int* __restrict__ slot_e, int* __restrict__ blockCounts) {
  __shared__ int cnt[NE];
  if (threadIdx.x < NE) cnt[threadIdx.x] = 0;
  __syncthreads();
  int i = blockIdx.x * 256 + threadIdx.x;
  atomicAdd(&cnt[slot_e[i]], 1);
  __syncthreads();
  if (threadIdx.x < NE) blockCounts[threadIdx.x * NB + blockIdx.x] = cnt[threadIdx.x];
}

__global__ void scan_kernel(const int* __restrict__ blockCounts, int* __restrict__ startEB,
                            int* __restrict__ tile_e, int* __restrict__ tile_row0,
                            int* __restrict__ tile_cnt, int* __restrict__ tileCount) {
  __shared__ int totals[NE];
  __shared__ int bases[NE];
  int t = threadIdx.x;
  if (t < NE) {
    int run = 0;
    for (int b = 0; b < NB; ++b) run += blockCounts[t * NB + b];
    totals[t] = run;
  }
  __syncthreads();
  if (t == 0) {
    int base = 0, nt = 0;
    for (int e = 0; e < NE; ++e) {
      bases[e] = base;
      int tot = totals[e];
      for (int i = 0; i < tot; i += MT) {
        tile_e[nt] = e;
        tile_row0[nt] = base + i;
        tile_cnt[nt] = (tot - i < MT) ? (tot - i) : MT;
        ++nt;
      }
      base += tot;
    }
    *tileCount = nt;
  }
  __syncthreads();
  if (t < NE) {
    int run = bases[t];
    for (int b = 0; b < NB; ++b) {
      startEB[t * NB + b] = run;
      run += blockCounts[t * NB + b];
    }
  }
}

__global__ void place_kernel(const int* __restrict__ slot_e, const float* __restrict__ slot_w,
                             const int* __restrict__ startEB,
                             int* __restrict__ perm_token, float* __restrict__ perm_w,
                             int* __restrict__ inv) {
  __shared__ int se[256];
  __shared__ float sw[256];
  int b = blockIdx.x;
  for (int i = threadIdx.x; i < 256; i += 64) {
    se[i] = slot_e[b * 256 + i];
    sw[i] = slot_w[b * 256 + i];
  }
  __syncthreads();
  int e = threadIdx.x;
  if (e < NE) {
    int pos = startEB[e * NB + b];
    for (int i = 0; i < 256; ++i) {
      if (se[i] == e) {
        perm_token[pos] = (b * 256 + i) >> 3;
        perm_w[pos] = sw[i];
        inv[b * 256 + i] = pos;
        ++pos;
      }
    }
  }
}

// ---------------- 4-window 256x256 grouped GEMM machinery (round-7, proven) ----------------
// One window per (buf,kk) region: lgkm-drain + vmcnt(N) + single barrier, then two
// 16-MFMA sub-phases with free compiler scheduling. vmcnt(8) steady, 8/8/4/0 tail.

#define GUMM(AR, M_)                                                                   \
  acc[M_][0] = __builtin_amdgcn_mfma_f32_16x16x32_bf16(AR, b0, acc[M_][0], 0, 0, 0);   \
  acc[M_][1] = __builtin_amdgcn_mfma_f32_16x16x32_bf16(AR, b1, acc[M_][1], 0, 0, 0);   \
  acc[M_][2] = __builtin_amdgcn_mfma_f32_16x16x32_bf16(AR, b2, acc[M_][2], 0, 0, 0);   \
  acc[M_][3] = __builtin_amdgcn_mfma_f32_16x16x32_bf16(AR, b3, acc[M_][3], 0, 0, 0);

#define GWIN(BUF, KK, VM, S1, S2)                                                      \
  do {                                                                                 \
    asm volatile("s_waitcnt lgkmcnt(0)" ::: "memory");                                 \
    __builtin_amdgcn_sched_barrier(0);                                                 \
    asm volatile("s_waitcnt vmcnt(" #VM ")" ::: "memory");                             \
    __builtin_amdgcn_s_barrier();                                                      \
    const u16* Ap_ = &SA[BUF][KK][abase];                                              \
    const u16* Bp_ = &SB[BUF][KK][0];                                                  \
    bf16x8 a0_ = *(const bf16x8*)(Ap_);                                                \
    bf16x8 a1_ = *(const bf16x8*)(Ap_ + 512);                                          \
    bf16x8 a2_ = *(const bf16x8*)(Ap_ + 1024);                                         \
    bf16x8 a3_ = *(const bf16x8*)(Ap_ + 1536);                                         \
    bf16x8 b0 = *(const bf16x8*)(Bp_ + boff0);                                         \
    bf16x8 b1 = *(const bf16x8*)(Bp_ + boff1);                                         \
    bf16x8 b2 = *(const bf16x8*)(Bp_ + boff2);                                         \
    bf16x8 b3 = *(const bf16x8*)(Bp_ + boff3);                                         \
    S1;                                                                                \
    __builtin_amdgcn_s_setprio(1);                                                     \
    GUMM(a0_, 0) GUMM(a1_, 1) GUMM(a2_, 2) GUMM(a3_, 3)                                \
    __builtin_amdgcn_s_setprio(0);                                                     \
    bf16x8 c0_ = *(const bf16x8*)(Ap_ + 2048);                                         \
    bf16x8 c1_ = *(const bf16x8*)(Ap_ + 2560);                                         \
    bf16x8 c2_ = *(const bf16x8*)(Ap_ + 3072);                                         \
    bf16x8 c3_ = *(const bf16x8*)(Ap_ + 3584);                                         \
    S2;                                                                                \
    __builtin_amdgcn_s_setprio(1);                                                     \
    GUMM(c0_, 4) GUMM(c1_, 5) GUMM(c2_, 6) GUMM(c3_, 7)                                \
    __builtin_amdgcn_s_setprio(0);                                                     \
  } while (0)

// ---------------- gate_up GEMM: 256 slots x (128 gate + 128 up cols) ----------------
__global__ __launch_bounds__(512, 2) void gu_fast(
    const u16* __restrict__ xb, const u16* __restrict__ wgub,
    const int* __restrict__ perm_token,
    const int* __restrict__ tile_e, const int* __restrict__ tile_row0,
    const int* __restrict__ tile_cnt, const int* __restrict__ tileCount,
    u16* __restrict__ h_perm) {
  // XCD clustering: flat%8 = XCD; give each XCD a contiguous 36-tile chunk.
  int flat = blockIdx.x + blockIdx.y * 6;       // NWG = 6*288 = 1728, %8 == 0
  int xcd = flat & 7;
  int j = flat >> 3;                            // 0..215
  int tile = xcd * 36 + j / 6;
  int n0g = (j % 6) * 128;
  if (tile >= *tileCount) return;
  int e = tile_e[tile], row0 = tile_row0[tile], cnt = tile_cnt[tile];
  __shared__ __align__(16) u16 SA[2][2][8192];   // [buf][kk][256 rows x 32 K]
  __shared__ __align__(16) u16 SB[2][2][8192];   // rows 0-127 gate, 128-255 up
  __shared__ int toks[256];
  int tid = threadIdx.x;
  if (tid < 256) {
    int idx = row0 + tid;
    if (idx > NSLOT - 1) idx = NSLOT - 1;
    toks[tid] = perm_token[idx];
  }
  __syncthreads();
  int wave = tid >> 6, lane = tid & 63;
  int wr = wave >> 2, wc = wave & 3;
  int lr = lane & 15, lk = lane >> 4;
  int sr0 = tid >> 2;                       // rows 0..127 (+128 for 2nd load)
  int sc0 = (tid & 3) ^ ((tid >> 3) & 3);   // pre-swizzled K-chunk
  const u16* gA0 = xb + (size_t)toks[sr0] * HID + sc0 * 8;
  const u16* gA1 = xb + (size_t)toks[128 + sr0] * HID + sc0 * 8;
  const u16* wgb = wgub + (size_t)e * (2 * DFF) * HID;
  const u16* gB0 = wgb + (size_t)(n0g + sr0) * HID + sc0 * 8;          // gate row
  const u16* gB1 = wgb + (size_t)(DFF + n0g + sr0) * HID + sc0 * 8;    // up row
  int d0 = tid * 8, d1 = 4096 + tid * 8;    // linear LDS dests (u16 units)

  int slot8 = (lk ^ ((lr >> 1) & 3)) * 8;
  int abase = (wr * 128 + lr) * 32 + slot8;
  int boff0 = (wc * 32 + 0 * 16 + lr) * 32 + slot8;          // gate
  int boff1 = (wc * 32 + 1 * 16 + lr) * 32 + slot8;          // gate
  int boff2 = (128 + wc * 32 + 0 * 16 + lr) * 32 + slot8;    // up
  int boff3 = (128 + wc * 32 + 1 * 16 + lr) * 32 + slot8;    // up

  f32x4 acc[8][4];
  f32x4 zero = {0.f, 0.f, 0.f, 0.f};
#pragma unroll
  for (int m = 0; m < 8; ++m)
#pragma unroll
    for (int n = 0; n < 4; ++n) acc[m][n] = zero;

#define GU_SGA(BUF, KK, KT) do { \
    gload16(gA0 + (KT) + (KK) * 32, &SA[BUF][KK][d0]); \
    gload16(gA1 + (KT) + (KK) * 32, &SA[BUF][KK][d1]); } while (0)
#define GU_SGB(BUF, KK, KT) do { \
    gload16(gB0 + (KT) + (KK) * 32, &SB[BUF][KK][d0]); \
    gload16(gB1 + (KT) + (KK) * 32, &SB[BUF][KK][d1]); } while (0)

  // prologue: t0 full (buf0), t1.kk0 (buf1) = 12 loads in flight
  GU_SGA(0, 0, 0); GU_SGB(0, 0, 0);
  GU_SGA(0, 1, 0); GU_SGB(0, 1, 0);
  GU_SGA(1, 0, 64); GU_SGB(1, 0, 64);

  const int NKT = HID / 64;   // 32
  const int NI = NKT / 2;     // 16
  for (int it = 0; it < NI - 1; ++it) {
    int ktA = (2 * it + 1) * 64;
    int ktB = (2 * it + 2) * 64;
    int ktC = (2 * it + 3) * 64;
    GWIN(0, 0, 8, GU_SGA(1, 1, ktA), GU_SGB(1, 1, ktA));
    GWIN(0, 1, 8, GU_SGA(0, 0, ktB), GU_SGB(0, 0, ktB));
    GWIN(1, 0, 8, GU_SGA(0, 1, ktB), GU_SGB(0, 1, ktB));
    GWIN(1, 1, 8, GU_SGA(1, 0, ktC), GU_SGB(1, 0, ktC));
  }
  {
    int ktA = (2 * (NI - 1) + 1) * 64;
    GWIN(0, 0, 8, GU_SGA(1, 1, ktA), GU_SGB(1, 1, ktA));
    GWIN(0, 1, 8, (void)0, (void)0);
    GWIN(1, 0, 4, (void)0, (void)0);
    GWIN(1, 1, 0, (void)0, (void)0);
  }

  // epilogue: h = silu(g) * u ; acc[m][0,1]=gate cols, acc[m][2,3]=up cols
#pragma unroll
  for (int m = 0; m < 8; ++m)
#pragma unroll
    for (int i = 0; i < 4; ++i) {
      int row = wr * 128 + m * 16 + lk * 4 + i;
      if (row < cnt) {
#pragma unroll
        for (int nf = 0; nf < 2; ++nf) {
          int col = n0g + wc * 32 + nf * 16 + lr;
          float g = acc[m][nf][i], u = acc[m][nf + 2][i];
          float h = g / (1.f + __expf(-g)) * u;
          h_perm[(size_t)(row0 + row) * DFF + col] = f2bf(h);
        }
      }
    }
#undef GU_SGA
#undef GU_SGB
}

// ---------------- down GEMM: 256 slots x 256 hid cols -> yp (fp16) ----------------
__global__ __launch_bounds__(512, 2) void down_fast(
    const u16* __restrict__ h_perm, const u16* __restrict__ wdb,
    const float* __restrict__ perm_w,
    const int* __restrict__ tile_e, const int* __restrict__ tile_row0,
    const int* __restrict__ tile_cnt, const int* __restrict__ tileCount,
    _Float16* __restrict__ yp) {
  int flat = blockIdx.x + blockIdx.y * 8;       // NWG = 8*288 = 2304, %8 == 0
  int xcd = flat & 7;
  int j = flat >> 3;                            // 0..287
  int tile = xcd * 36 + j / 8;
  int n0 = (j % 8) * 256;
  if (tile >= *tileCount) return;
  int e = tile_e[tile], row0 = tile_row0[tile], cnt = tile_cnt[tile];
  __shared__ __align__(16) u16 SA[2][2][8192];
  __shared__ __align__(16) u16 SB[2][2][8192];
  __shared__ float wts[256];
  int tid = threadIdx.x;
  if (tid < 256) {
    int idx = row0 + tid;
    if (idx > NSLOT - 1) idx = NSLOT - 1;
    wts[tid] = perm_w[idx];
  }
  __syncthreads();
  int wave = tid >> 6, lane = tid & 63;
  int wr = wave >> 2, wc = wave & 3;
  int lr = lane & 15, lk = lane >> 4;
  int sr0 = tid >> 2;
  int sc0 = (tid & 3) ^ ((tid >> 3) & 3);
  int ia0 = row0 + sr0;       if (ia0 > NSLOT - 1) ia0 = NSLOT - 1;
  int ia1 = row0 + 128 + sr0; if (ia1 > NSLOT - 1) ia1 = NSLOT - 1;
  const u16* gA0 = h_perm + (size_t)ia0 * DFF + sc0 * 8;
  const u16* gA1 = h_perm + (size_t)ia1 * DFF + sc0 * 8;
  const u16* wb = wdb + (size_t)e * HID * DFF;
  const u16* gB0 = wb + (size_t)(n0 + sr0) * DFF + sc0 * 8;
  const u16* gB1 = wb + (size_t)(n0 + 128 + sr0) * DFF + sc0 * 8;
  int d0 = tid * 8, d1 = 4096 + tid * 8;

  int slot8 = (lk ^ ((lr >> 1) & 3)) * 8;
  int abase = (wr * 128 + lr) * 32 + slot8;
  int boff0 = (wc * 64 + 0 * 16 + lr) * 32 + slot8;
  int boff1 = (wc * 64 + 1 * 16 + lr) * 32 + slot8;
  int boff2 = (wc * 64 + 2 * 16 + lr) * 32 + slot8;
  int boff3 = (wc * 64 + 3 * 16 + lr) * 32 + slot8;

  f32x4 acc[8][4];
  f32x4 zero = {0.f, 0.f, 0.f, 0.f};
#pragma unroll
  for (int m = 0; m < 8; ++m)
#pragma unroll
    for (int n = 0; n < 4; ++n) acc[m][n] = zero;

#define DN_SGA(BUF, KK, KT) do { \
    gload16(gA0 + (KT) + (KK) * 32, &SA[BUF][KK][d0]); \
    gload16(gA1 + (KT) + (KK) * 32, &SA[BUF][KK][d1]); } while (0)
#define DN_SGB(BUF, KK, KT) do { \
    gload16(gB0 + (KT) + (KK) * 32, &SB[BUF][KK][d0]); \
    gload16(gB1 + (KT) + (KK) * 32, &SB[BUF][KK][d1]); } while (0)

  DN_SGA(0, 0, 0); DN_SGB(0, 0, 0);
  DN_SGA(0, 1, 0); DN_SGB(0, 1, 0);
  DN_SGA(1, 0, 64); DN_SGB(1, 0, 64);

  const int NKT = DFF / 64;   // 12
  const int NI = NKT / 2;     // 6
  for (int it = 0; it < NI - 1; ++it) {
    int ktA = (2 * it + 1) * 64;
    int ktB = (2 * it + 2) * 64;
    int ktC = (2 * it + 3) * 64;
    GWIN(0, 0, 8, DN_SGA(1, 1, ktA), DN_SGB(1, 1, ktA));
    GWIN(0, 1, 8, DN_SGA(0, 0, ktB), DN_SGB(0, 0, ktB));
    GWIN(1, 0, 8, DN_SGA(0, 1, ktB), DN_SGB(0, 1, ktB));
    GWIN(1, 1, 8, DN_SGA(1, 0, ktC), DN_SGB(1, 0, ktC));
  }
  {
    int ktA = (2 * (NI - 1) + 1) * 64;
    GWIN(0, 0, 8, DN_SGA(1, 1, ktA), DN_SGB(1, 1, ktA));
    GWIN(0, 1, 8, (void)0, (void)0);
    GWIN(1, 0, 4, (void)0, (void)0);
    GWIN(1, 1, 0, (void)0, (void)0);
  }

#pragma unroll
  for (int m = 0; m < 8; ++m)
#pragma unroll
    for (int i = 0; i < 4; ++i) {
      int row = wr * 128 + m * 16 + lk * 4 + i;
      if (row < cnt) {
        float wt = wts[row];
#pragma unroll
        for (int nf = 0; nf < 4; ++nf) {
          int col = n0 + wc * 64 + nf * 16 + lr;
          yp[(size_t)(row0 + row) * HID + col] = (_Float16)(acc[m][nf][i] * wt);
        }
      }
    }
#undef DN_SGA
#undef DN_SGB
}

// ---------------- per-token gather-reduce of 8 slots ----------------
__global__ void reduce_kernel(const _Float16* __restrict__ yp, const int* __restrict__ inv,
                              float* __restrict__ y) {
  int t = blockIdx.x;
  __shared__ int pos[8];
  if (threadIdx.x < 8) pos[threadIdx.x] = inv[t * 8 + threadIdx.x];
  __syncthreads();
  int c = threadIdx.x * 8;
  float s[8] = {0.f, 0.f, 0.f, 0.f, 0.f, 0.f, 0.f, 0.f};
#pragma unroll
  for (int j = 0; j < 8; ++j) {
    uint4 v = *reinterpret_cast<const uint4*>(yp + (size_t)pos[j] * HID + c);
    const u16* p = reinterpret_cast<const u16*>(&v);
#pragma unroll
    for (int k = 0; k < 8; ++k) {
      _Float16 h;
      u16 us = p[k];
      __builtin_memcpy(&h, &us, 2);
      s[k] += (float)h;
    }
  }
  float* yo = y + (size_t)t * HID + c;
  float4 o0 = {s[0], s[1], s[2], s[3]};
  float4 o1 = {s[4], s[5], s[6], s[7]};
  *reinterpret_cast<float4*>(yo) = o0;
  *reinterpret_cast<float4*>(yo + 4) = o1;
}

extern "C" void kernel_launch(void* const* d_in, const int* in_sizes, int n_in,
                              void* d_out, int out_size, void* d_ws, size_t ws_size,
                              hipStream_t stream) {
  const float* x = (const float*)d_in[0];
  const float* gw = (const float*)d_in[1];
  const float* wgu = (const float*)d_in[2];
  const float* wd = (const float*)d_in[3];
  const float* sim = (const float*)d_in[4];
  float* y = (float*)d_out;

  char* ws = (char*)d_ws;
  size_t off = 0;
  auto alloc = [&](size_t bytes) {
    char* p = ws + off;
    off += (bytes + 255) & ~(size_t)255;
    return p;
  };
  u16* xb = (u16*)alloc((size_t)NTOK * HID * 2);
  u16* h_perm = (u16*)alloc((size_t)NSLOT * DFF * 2);
  int* slot_e = (int*)alloc(NSLOT * 4);
  float* slot_w = (float*)alloc(NSLOT * 4);
  int* perm_token = (int*)alloc(NSLOT * 4);
  float* perm_w = (float*)alloc(NSLOT * 4);
  int* inv = (int*)alloc(NSLOT * 4);
  int* blockCounts = (int*)alloc(NE * NB * 4);
  int* startEB = (int*)alloc(NE * NB * 4);
  int* tile_e = (int*)alloc(MAX_TILES * 4);
  int* tile_row0 = (int*)alloc(MAX_TILES * 4);
  int* tile_cnt = (int*)alloc(MAX_TILES * 4);
  int* tileCount = (int*)alloc(4);

  // bf16 weights + fp16 per-slot down output (yp aliases wgu_b region)
  size_t wgu_elems = (size_t)NE * 2 * DFF * HID;
  size_t wd_elems = (size_t)NE * HID * DFF;
  size_t region_bytes = (size_t)NSLOT * HID * 2;  // yp (268MB) > wgu_b (201MB)
  u16* wd_b = (u16*)alloc(wd_elems * 2);
  char* region = alloc(region_bytes);
  u16* wgu_b = (u16*)region;
  _Float16* yp = (_Float16*)region;
  if (off > ws_size) return;  // insufficient workspace: fail loudly

  router_kernel<<<NTOK, 256, 0, stream>>>(x, gw, sim, slot_e, slot_w, xb);
  hist_kernel<<<NB, 256, 0, stream>>>(slot_e, blockCounts);
  scan_kernel<<<1, 64, 0, stream>>>(blockCounts, startEB, tile_e, tile_row0, tile_cnt, tileCount);
  place_kernel<<<NB, 64, 0, stream>>>(slot_e, slot_w, startEB, perm_token, perm_w, inv);

  convert2_kernel<<<8192, 256, 0, stream>>>(wgu, wgu_b, (int)(wgu_elems / 4),
                                            wd, wd_b, (int)(wd_elems / 4));
  gu_fast<<<dim3(DFF / 128, MAX_TILES), 512, 0, stream>>>(
      xb, wgu_b, perm_token, tile_e, tile_row0, tile_cnt, tileCount, h_perm);
  down_fast<<<dim3(HID / 256, MAX_TILES), 512, 0, stream>>>(
      h_perm, wd_b, perm_w, tile_e, tile_row0, tile_cnt, tileCount, yp);
  reduce_kernel<<<NTOK, 256, 0, stream>>>(yp, inv, y);
}